// Round 7
// baseline (1011.936 us; speedup 1.0000x reference)
//
#include <hip/hip_runtime.h>
#include <math.h>

#define BB 8
#define NN 4096
#define CC 256
#define DD 64
#define MM 1024
#define KNB 16
#define OC 259
#define CHUNK 128
#define NCHUNK 8

typedef unsigned long long ull;

// Dispatch roles (main grid 1032, aux dispatch 2585):
//   blk [0,8)       : FPS chunk c_fps (8 blocks, 1 batch each)
//   aux dispatch    : blk [8,2585) -> 2577 aux units
//   main dispatches : blk [8,1032) -> fuse chunk c_fuse (1024 blocks,
//                     each block computes its own KNN with wave 0 first)
// Pipeline lag is 1: D_c = FPS c || fuse c-1. Tail = single fuse dispatch.
// Static LDS = 49,728 B (FPS role; fuse role = 35,600 with dbuf aliased
// over W12_l) -> 3 blocks/CU with __launch_bounds__(256,3).
#define GRID_MAIN 1032
#define GRID_AUX 2585
#define AUX_G2 512

// ---------------------------------------------------------------------------
// aux units (verbatim from verified round-0 phase1 roles) ----------------
__device__ __forceinline__ void g2_unit(
    int u, int tid, char* smem, const float* fm, const float* aw1,
    const float* g2v, const float* v2, float* G2) {
  float (*a_l)[68] = (float(*)[68])smem;
  float (*b_l)[68] = (float(*)[68])(smem + 64 * 68 * 4);
  int b = u >> 6;
  int n0 = (u & 63) * 64;
  int rr = tid >> 4, q4 = tid & 15;
  float s2v[4];
#pragma unroll
  for (int j = 0; j < 4; ++j)
    s2v[j] = g2v[q4 * 4 + j] * rsqrtf(v2[q4 * 4 + j] + 1e-5f);
  float acc[4][4];
#pragma unroll
  for (int q = 0; q < 4; ++q)
#pragma unroll
    for (int x = 0; x < 4; ++x) acc[q][x] = 0.f;
  for (int c0 = 0; c0 < 256; c0 += 64) {
    __syncthreads();
#pragma unroll
    for (int rep = 0; rep < 4; ++rep) {
      int cc = rr + rep * 16;
      *(float4*)&a_l[cc][q4 * 4] =
          *(const float4*)&fm[((size_t)b * CC + c0 + cc) * NN + n0 + q4 * 4];
      float bv[4];
#pragma unroll
      for (int j = 0; j < 4; ++j)
        bv[j] = aw1[(q4 * 4 + j) * 256 + c0 + cc] * s2v[j];
      *(float4*)&b_l[cc][q4 * 4] = make_float4(bv[0], bv[1], bv[2], bv[3]);
    }
    __syncthreads();
#pragma unroll 8
    for (int kk = 0; kk < 64; ++kk) {
      float4 a4 = *(const float4*)&a_l[kk][rr * 4];
      float4 b4 = *(const float4*)&b_l[kk][q4 * 4];
      float av[4] = {a4.x, a4.y, a4.z, a4.w};
#pragma unroll
      for (int q = 0; q < 4; ++q) {
        acc[q][0] += av[q] * b4.x;
        acc[q][1] += av[q] * b4.y;
        acc[q][2] += av[q] * b4.z;
        acc[q][3] += av[q] * b4.w;
      }
    }
  }
#pragma unroll
  for (int q = 0; q < 4; ++q)
    *(float4*)&G2[((size_t)b * NN + n0 + rr * 4 + q) * 64 + q4 * 4] =
        make_float4(acc[q][0], acc[q][1], acc[q][2], acc[q][3]);
}

__device__ __forceinline__ void prep_unit(
    int tid, const float* pw1, const float* pb1, const float* g1,
    const float* bb1, const float* m1, const float* v1, const float* pw2,
    const float* aw1, const float* g2v, const float* bb2, const float* m2,
    const float* v2, const float* aw2, const float* ab1, float* w1f,
    float* b1f, float* ab1f, float* pw2t, float* aw1t, float* aw2t) {
  if (tid < 64) {
    float s = g1[tid] * rsqrtf(v1[tid] + 1e-5f);
    w1f[tid * 4 + 0] = pw1[tid * 3 + 0] * s;
    w1f[tid * 4 + 1] = pw1[tid * 3 + 1] * s;
    w1f[tid * 4 + 2] = pw1[tid * 3 + 2] * s;
    w1f[tid * 4 + 3] = 0.f;
    b1f[tid] = (pb1[tid] - m1[tid]) * s + bb1[tid];
    float s2 = g2v[tid] * rsqrtf(v2[tid] + 1e-5f);
    ab1f[tid] = (ab1[tid] - m2[tid]) * s2 + bb2[tid];
  }
  for (int x = tid; x < 64 * 256; x += 256) {
    int i = x >> 8, c = x & 255;
    pw2t[x] = pw2[c * 64 + i];
  }
  for (int x = tid; x < 256 * 64; x += 256) {
    int c = x >> 6, d = x & 63;
    float s2 = g2v[d] * rsqrtf(v2[d] + 1e-5f);
    aw1t[x] = aw1[d * 256 + c] * s2;
  }
  for (int x = tid; x < 64 * OC; x += 256) {
    int i = x / OC, o = x % OC;
    aw2t[i * 260 + o] = aw2[o * 64 + i];
  }
}

__device__ __forceinline__ void w12_unit(
    int w, int tid, const float* pw2, const float* aw1, const float* g2v,
    const float* v2, float* W12t) {
  int i = tid & 63;
  int d = w * 4 + (tid >> 6);
  float s2 = g2v[d] * rsqrtf(v2[d] + 1e-5f);
  const float* arow = aw1 + d * 256;
  float s = 0.f;
#pragma unroll 4
  for (int c = 0; c < 256; ++c) s += pw2[c * 64 + i] * arow[c];
  W12t[i * 64 + d] = s * s2;
}

__device__ __forceinline__ void transpose_unit(
    int rb, int tid, char* smem, const float* fm, float* fm_t) {
  float (*tile)[65] = (float(*)[65])smem;
  int b = rb >> 8;
  int rem = rb & 255;
  int c0 = (rem >> 6) * 64;
  int n0 = (rem & 63) * 64;
  const float* src = fm + (size_t)b * CC * NN;
  float* dst = fm_t + (size_t)b * NN * CC;
  int tx = tid & 63, ty = tid >> 6;
  for (int r = ty; r < 64; r += 4)
    tile[r][tx] = src[(size_t)(c0 + r) * NN + n0 + tx];
  __syncthreads();
  for (int r = ty; r < 64; r += 4)
    dst[(size_t)(n0 + r) * CC + c0 + tx] = tile[tx][r];
}

// KNN (verbatim round-0 phase2 loop; one wave, kidx written to LDS) ------
__device__ __forceinline__ void knn_to_lds(
    int b, int m, int lane, float* dbuf, const float* verts,
    const int* fpsi, int* kidx) {
  const float* vb = verts + (size_t)b * 3 * NN;
  int jm = fpsi[b * MM + m];
  float kx = vb[jm], ky = vb[NN + jm], kz = vb[2 * NN + jm];
  float kn = kx * kx + ky * ky + kz * kz;
  float v1 = INFINITY, v2 = INFINITY;
  int i1 = -1, i2 = -1;
  for (int t = 0; t < 64; ++t) {
    int j = t * 64 + lane;
    float x = vb[j], y = vb[NN + j], z = vb[2 * NN + j];
    float xn = x * x + y * y + z * z;
    float d = kn + xn - 2.0f * (kx * x + ky * y + kz * z);
    dbuf[lane * 65 + t] = d;
    if (d < v1) { v2 = v1; i2 = i1; v1 = d; i1 = j; }
    else if (d < v2) { v2 = d; i2 = j; }
  }
  for (int it = 0; it < KNB; ++it) {
    float rv = v1;
    int ri = i1;
#pragma unroll
    for (int off = 32; off >= 1; off >>= 1) {
      float ov = __shfl_down(rv, off, 64);
      int oi = __shfl_down(ri, off, 64);
      if (ov < rv || (ov == rv && oi < ri)) { rv = ov; ri = oi; }
    }
    ri = __shfl(ri, 0, 64);
    if (lane == 0) kidx[it] = ri;
    if (i1 == ri) {
      dbuf[lane * 65 + (ri >> 6)] = INFINITY;
      v1 = v2; i1 = i2;
      v2 = INFINITY; i2 = -1;
      if (i1 < 0) {
        v1 = INFINITY; v2 = INFINITY; i1 = -1; i2 = -1;
        for (int t = 0; t < 64; ++t) {
          float d = dbuf[lane * 65 + t];
          int j = t * 64 + lane;
          if (d < v1) { v2 = v1; i2 = i1; v1 = d; i1 = j; }
          else if (d < v2) { v2 = d; i2 = j; }
        }
      }
    }
  }
}

// fuse item (round-0 body; kidx precomputed by wave 0, dbuf aliases W12_l)
struct FuseS {                 // 35,600 B
  float W12_l[64][68];         // phase A: aliased as KNN dbuf (16,640 B)
  float h_l[16][68];
  float hT_l[64][20];
  float h2T_l[64][20];
  float vmp[4][64];
  float vm_l[64];
  float kfpb[256];
  float pb2_l[256];
  float gp[3][16];
  float kp[4];
  int kidx[16];
};

__device__ __forceinline__ void fuse_item(
    int b, int m, int tid, char* smem, const float* verts,
    const float* fm_t, const float* G2, const int* fpsi,
    const float* w1f, const float* b1f, const float* ab1f,
    const float* aw1t, const float* W12t, const float* pw2t,
    const float* pb2, const float* aw2t, const float* ab2, float* out) {
  FuseS* S = (FuseS*)smem;
  const float* vb = verts + (size_t)b * 3 * NN;
  const float* fb = fm_t + (size_t)b * NN * CC;

  // ---- phase A: wave 0 computes this item's 16-NN into S->kidx.
  if (tid < 64)
    knn_to_lds(b, m, tid, (float*)S->W12_l, verts, fpsi, S->kidx);
  __syncthreads();

  // ---- phase B: verbatim fuse body (kidx already in LDS).
  int jm = fpsi[b * MM + m];
  S->kfpb[tid] = fb[(size_t)jm * CC + tid] + pb2[tid];
  S->pb2_l[tid] = pb2[tid];
  if (tid < 3) S->kp[tid] = vb[tid * NN + jm];
  __syncthreads();

  if (tid < 48) {
    int c = tid >> 4, k = tid & 15;
    S->gp[c][k] = vb[c * NN + S->kidx[k]];
  }
  {
    int i = tid >> 4, d4 = tid & 15;
#pragma unroll
    for (int rep = 0; rep < 4; ++rep)
      *(float4*)&S->W12_l[i + rep * 16][d4 * 4] =
          *(const float4*)&W12t[(i + rep * 16) * 64 + d4 * 4];
  }
  {
    int d = tid & 63, part = tid >> 6;
    float acc = 0.f;
#pragma unroll 4
    for (int cc = 0; cc < 64; ++cc) {
      int c = part * 64 + cc;
      acc += aw1t[c * 64 + d] * S->kfpb[c];
    }
    S->vmp[part][d] = acc;
  }
  __syncthreads();
  if (tid < 64)
    S->vm_l[tid] = S->vmp[0][tid] + S->vmp[1][tid] + S->vmp[2][tid] +
                   S->vmp[3][tid] + ab1f[tid];

  {
    int d = tid & 63, part = tid >> 6;
    float wd0 = w1f[d * 4 + 0], wd1 = w1f[d * 4 + 1], wd2 = w1f[d * 4 + 2];
    float bd = b1f[d];
#pragma unroll
    for (int j = 0; j < 4; ++j) {
      int k = part * 4 + j;
      float hv = wd0 * (S->kp[0] - S->gp[0][k]) +
                 wd1 * (S->kp[1] - S->gp[1][k]) +
                 wd2 * (S->kp[2] - S->gp[2][k]) + bd;
      hv = (hv > 0.f) ? hv : 0.2f * hv;
      S->h_l[k][d] = hv;
      S->hT_l[d][k] = hv;
    }
  }
  __syncthreads();

  {
    int k = tid & 15, d2 = tid >> 4;
    float4 g4 =
        *(const float4*)&G2[((size_t)b * NN + S->kidx[k]) * 64 + d2 * 4];
    float a0 = 0.f, a1 = 0.f, a2 = 0.f, a3 = 0.f;
#pragma unroll 4
    for (int i = 0; i < 64; ++i) {
      float hv = S->h_l[k][i];
      float4 w4 = *(const float4*)&S->W12_l[i][d2 * 4];
      a0 += hv * w4.x; a1 += hv * w4.y; a2 += hv * w4.z; a3 += hv * w4.w;
    }
    float4 v4 = *(const float4*)&S->vm_l[d2 * 4];
    float r0 = v4.x - g4.x + a0;
    float r1 = v4.y - g4.y + a1;
    float r2 = v4.z - g4.z + a2;
    float r3 = v4.w - g4.w + a3;
    S->h2T_l[d2 * 4 + 0][k] = (r0 > 0.f) ? r0 : 0.2f * r0;
    S->h2T_l[d2 * 4 + 1][k] = (r1 > 0.f) ? r1 : 0.2f * r1;
    S->h2T_l[d2 * 4 + 2][k] = (r2 > 0.f) ? r2 : 0.2f * r2;
    S->h2T_l[d2 * 4 + 3][k] = (r3 > 0.f) ? r3 : 0.2f * r3;
  }
  __syncthreads();

  if (tid < 3) {
    float lg[16];
    float bias = ab2[tid];
#pragma unroll
    for (int k = 0; k < 16; ++k) lg[k] = bias;
    const float* wp = aw2t + tid;
    for (int i = 0; i < 64; ++i) {
      float wv = wp[i * 260];
      float4 ha = *(const float4*)&S->h2T_l[i][0];
      float4 hb = *(const float4*)&S->h2T_l[i][4];
      float4 hc = *(const float4*)&S->h2T_l[i][8];
      float4 hd = *(const float4*)&S->h2T_l[i][12];
      lg[0] += wv * ha.x;  lg[1] += wv * ha.y;  lg[2] += wv * ha.z;  lg[3] += wv * ha.w;
      lg[4] += wv * hb.x;  lg[5] += wv * hb.y;  lg[6] += wv * hb.z;  lg[7] += wv * hb.w;
      lg[8] += wv * hc.x;  lg[9] += wv * hc.y;  lg[10] += wv * hc.z; lg[11] += wv * hc.w;
      lg[12] += wv * hd.x; lg[13] += wv * hd.y; lg[14] += wv * hd.z; lg[15] += wv * hd.w;
    }
    float mx = lg[0];
#pragma unroll
    for (int k = 1; k < 16; ++k) mx = fmaxf(mx, lg[k]);
    float sum = 0.f;
#pragma unroll
    for (int k = 0; k < 16; ++k) { lg[k] = __expf(lg[k] - mx); sum += lg[k]; }
    float inv = 1.f / sum;
    float a2 = 0.f;
#pragma unroll
    for (int k = 0; k < 16; ++k) a2 += lg[k] * S->gp[tid][k];
    out[((size_t)b * OC + tid) * MM + m] = a2 * inv;
  }

  {
    int o = tid + 3;
    float gfv[16];
#pragma unroll
    for (int k = 0; k < 16; ++k)
      gfv[k] = fb[(size_t)S->kidx[k] * CC + tid];
    float lg[16];
    float bias = ab2[o];
#pragma unroll
    for (int k = 0; k < 16; ++k) lg[k] = bias;
    const float* wp = aw2t + o;
#pragma unroll 4
    for (int i = 0; i < 64; ++i) {
      float wv = wp[i * 260];
      float4 ha = *(const float4*)&S->h2T_l[i][0];
      float4 hb = *(const float4*)&S->h2T_l[i][4];
      float4 hc = *(const float4*)&S->h2T_l[i][8];
      float4 hd = *(const float4*)&S->h2T_l[i][12];
      lg[0] += wv * ha.x;  lg[1] += wv * ha.y;  lg[2] += wv * ha.z;  lg[3] += wv * ha.w;
      lg[4] += wv * hb.x;  lg[5] += wv * hb.y;  lg[6] += wv * hb.z;  lg[7] += wv * hb.w;
      lg[8] += wv * hc.x;  lg[9] += wv * hc.y;  lg[10] += wv * hc.z; lg[11] += wv * hc.w;
      lg[12] += wv * hd.x; lg[13] += wv * hd.y; lg[14] += wv * hd.z; lg[15] += wv * hd.w;
    }
    float mx = lg[0];
#pragma unroll
    for (int k = 1; k < 16; ++k) mx = fmaxf(mx, lg[k]);
    float sum = 0.f;
#pragma unroll
    for (int k = 0; k < 16; ++k) { lg[k] = __expf(lg[k] - mx); sum += lg[k]; }
    float inv = 1.f / sum;
#pragma unroll
    for (int k = 0; k < 16; ++k) lg[k] *= inv;
    float acc = 0.f;
#pragma unroll
    for (int k = 0; k < 16; ++k) acc += lg[k] * gfv[k];
    const float* pcol = pw2t + tid;
#pragma unroll 4
    for (int i = 0; i < 64; ++i) {
      float p = pcol[i * 256];
      float4 ha = *(const float4*)&S->hT_l[i][0];
      float4 hb = *(const float4*)&S->hT_l[i][4];
      float4 hc = *(const float4*)&S->hT_l[i][8];
      float4 hd = *(const float4*)&S->hT_l[i][12];
      float hw = lg[0] * ha.x + lg[1] * ha.y + lg[2] * ha.z + lg[3] * ha.w +
                 lg[4] * hb.x + lg[5] * hb.y + lg[6] * hb.z + lg[7] * hb.w +
                 lg[8] * hc.x + lg[9] * hc.y + lg[10] * hc.z + lg[11] * hc.w +
                 lg[12] * hd.x + lg[13] * hd.y + lg[14] * hd.z + lg[15] * hd.w;
      acc += p * hw;
    }
    out[((size_t)b * OC + o) * MM + m] = S->pb2_l[tid] + acc;
  }
}

// ---------------------------------------------------------------------------
// Pipelined dispatch kernel, lag-1: dispatch boundaries order
// FPS chunk c -> fuse chunk c (next dispatch, KNN computed in-block).
__global__ __launch_bounds__(256, 3) void pipe(
    const float* __restrict__ verts, const float* __restrict__ fm,
    const float* __restrict__ pw1, const float* __restrict__ pb1,
    const float* __restrict__ g1, const float* __restrict__ bb1,
    const float* __restrict__ m1, const float* __restrict__ v1,
    const float* __restrict__ pw2, const float* __restrict__ pb2,
    const float* __restrict__ aw1, const float* __restrict__ ab1,
    const float* __restrict__ g2v, const float* __restrict__ bb2,
    const float* __restrict__ m2, const float* __restrict__ v2,
    const float* __restrict__ aw2, const float* __restrict__ ab2,
    float* __restrict__ fm_t, float* __restrict__ G2,
    int* __restrict__ fpsi,
    float* __restrict__ w1f, float* __restrict__ b1f,
    float* __restrict__ ab1f, float* __restrict__ pw2t,
    float* __restrict__ aw1t, float* __restrict__ aw2t,
    float* __restrict__ W12t, float* __restrict__ dstate,
    int* __restrict__ fstate, float* __restrict__ out,
    int c_fps, int c_fuse, int aux_flag) {
  __shared__ __align__(16) char smem[49728];
  int blk = blockIdx.x;
  int tid = threadIdx.x;

  if (blk < 8) {
    // ---- FPS chunk (v5 loop body; indices buffered in LDS, bulk-stored)
    if (c_fps < 0) return;
    float* lx = (float*)smem;
    float* ly = lx + NN;
    float* lz = ly + NN;
    ull* wres = (ull*)(lz + NN);        // [2][4] = 64 B
    int* fps_l = (int*)(wres + 8);      // [CHUNK] = 512 B
    int b = blk;
    const float* vb = verts + (size_t)b * 3 * NN;
    float px[16], py[16], pz[16], dist[16];
#pragma unroll
    for (int r = 0; r < 16; ++r) {
      int j = tid + r * 256;
      px[r] = vb[j]; py[r] = vb[NN + j]; pz[r] = vb[2 * NN + j];
      lx[j] = px[r]; ly[j] = py[r]; lz[j] = pz[r];
    }
    int far;
    if (c_fps == 0) {
#pragma unroll
      for (int r = 0; r < 16; ++r) dist[r] = 1e10f;
      far = 0;
    } else {
#pragma unroll
      for (int r = 0; r < 16; ++r)
        dist[r] = dstate[(size_t)b * NN + tid + r * 256];
      far = fstate[b];
    }
    __syncthreads();
    int s0 = c_fps * CHUNK, s1 = s0 + CHUNK;
    for (int s = s0; s < s1; ++s) {
      if (tid == 0) fps_l[s - s0] = far;
      if (s == MM - 1) break;
      float cx = lx[far], cy = ly[far], cz = lz[far];
      float vmax = -1.0f;
#pragma unroll
      for (int r = 0; r < 16; ++r) {
        float dx = px[r] - cx, dy = py[r] - cy, dz = pz[r] - cz;
        float d = dx * dx + dy * dy + dz * dz;
        dist[r] = fminf(dist[r], d);
        vmax = fmaxf(vmax, dist[r]);
      }
#define VRED(CTRL)                                                            \
      {                                                                       \
        int o = __builtin_amdgcn_update_dpp(__float_as_int(vmax),             \
                                            __float_as_int(vmax), CTRL, 0xF,  \
                                            0xF, false);                      \
        vmax = fmaxf(vmax, __int_as_float(o));                                \
      }
      VRED(0x111) VRED(0x112) VRED(0x114) VRED(0x118) VRED(0x142) VRED(0x143)
#undef VRED
      float svmax =
          __int_as_float(__builtin_amdgcn_readlane(__float_as_int(vmax), 63));
      int minj = 0x7FFFFFFF;
#pragma unroll
      for (int r = 0; r < 16; ++r) {
        int cand = (dist[r] == svmax) ? (tid + r * 256) : 0x7FFFFFFF;
        minj = (cand < minj) ? cand : minj;
      }
#define IRED(CTRL)                                                            \
      {                                                                       \
        int o = __builtin_amdgcn_update_dpp(minj, minj, CTRL, 0xF, 0xF,       \
                                            false);                          \
        minj = (o < minj) ? o : minj;                                         \
      }
      IRED(0x111) IRED(0x112) IRED(0x114) IRED(0x118) IRED(0x142) IRED(0x143)
#undef IRED
      if ((tid & 63) == 63)
        wres[(s & 1) * 4 + (tid >> 6)] =
            ((ull)(unsigned)__float_as_int(svmax) << 12) |
            (ull)(4095 - minj);
      __syncthreads();
      int p = s & 1;
      ull k0 = wres[p * 4 + 0], k1 = wres[p * 4 + 1];
      ull k2 = wres[p * 4 + 2], k3 = wres[p * 4 + 3];
      ull a = (k0 > k1) ? k0 : k1;
      ull c = (k2 > k3) ? k2 : k3;
      a = (c > a) ? c : a;
      far = 4095 - (int)(a & 0xFFFull);
    }
    __syncthreads();
    for (int x = tid; x < CHUNK; x += 256) fpsi[b * MM + s0 + x] = fps_l[x];
    if (s1 < MM) {
#pragma unroll
      for (int r = 0; r < 16; ++r)
        dstate[(size_t)b * NN + tid + r * 256] = dist[r];
      if (tid == 0) fstate[b] = far;
    }
    return;
  }

  if (aux_flag) {
    // ---- D0 aux: u in [0,2577)
    int u = blk - 8;
    if (u < AUX_G2) {
      g2_unit(u, tid, smem, fm, aw1, g2v, v2, G2);
    } else if (u == AUX_G2) {
      prep_unit(tid, pw1, pb1, g1, bb1, m1, v1, pw2, aw1, g2v, bb2, m2, v2,
                aw2, ab1, w1f, b1f, ab1f, pw2t, aw1t, aw2t);
    } else if (u < AUX_G2 + 17) {
      w12_unit(u - (AUX_G2 + 1), tid, pw2, aw1, g2v, v2, W12t);
    } else {
      transpose_unit(u - (AUX_G2 + 17), tid, smem, fm, fm_t);
    }
    return;
  }

  {
    // ---- fuse chunk: 1024 blocks = 8 b x 128 m (b-minor for XCD spread)
    if (c_fuse < 0) return;
    int e = blk - 8;
    int b = e & 7;
    int m = c_fuse * CHUNK + (e >> 3);
    fuse_item(b, m, tid, smem, verts, fm_t, G2, fpsi, w1f, b1f, ab1f,
              aw1t, W12t, pw2t, pb2, aw2t, ab2, out);
  }
}

// ---------------------------------------------------------------------------
extern "C" void kernel_launch(void* const* d_in, const int* in_sizes, int n_in,
                              void* d_out, int out_size, void* d_ws,
                              size_t ws_size, hipStream_t stream) {
  (void)in_sizes; (void)n_in; (void)out_size; (void)ws_size;
  const float* verts = (const float*)d_in[0];
  const float* fm = (const float*)d_in[1];
  const float* pw1 = (const float*)d_in[2];
  const float* pb1 = (const float*)d_in[3];
  const float* g1 = (const float*)d_in[4];
  const float* bb1 = (const float*)d_in[5];
  const float* m1 = (const float*)d_in[6];
  const float* v1 = (const float*)d_in[7];
  const float* pw2 = (const float*)d_in[8];
  const float* pb2 = (const float*)d_in[9];
  const float* aw1 = (const float*)d_in[10];
  const float* ab1 = (const float*)d_in[11];
  const float* g2 = (const float*)d_in[12];
  const float* bb2 = (const float*)d_in[13];
  const float* m2 = (const float*)d_in[14];
  const float* v2 = (const float*)d_in[15];
  const float* aw2 = (const float*)d_in[16];
  const float* ab2 = (const float*)d_in[17];
  float* out = (float*)d_out;

  char* ws = (char*)d_ws;
  float* fm_t = (float*)ws;                               // 33,554,432 B
  float* G2 = (float*)(ws + 33554432);                    //  8,388,608 B
  int* fpsi = (int*)(ws + 41943040);                      //     32,768 B
  float* w1f = (float*)(ws + 42500096);
  float* b1f = w1f + 256;
  float* ab1f = b1f + 64;
  float* pw2t = ab1f + 64;
  float* aw1t = pw2t + 64 * 256;
  float* aw2t = aw1t + 256 * 64;
  float* W12t = aw2t + 64 * 260;
  float* dstate = (float*)(ws + 42715648);                //    131,072 B
  int* fstate = (int*)(ws + 42846720);                    //         32 B

#define LAUNCH(grid, cf, cz, ax)                                              \
  hipLaunchKernelGGL(pipe, dim3(grid), dim3(256), 0, stream, verts, fm, pw1,  \
                     pb1, g1, bb1, m1, v1, pw2, pb2, aw1, ab1, g2, bb2, m2,   \
                     v2, aw2, ab2, fm_t, G2, fpsi, w1f, b1f, ab1f,            \
                     pw2t, aw1t, aw2t, W12t, dstate, fstate, out, cf, cz, ax)

  LAUNCH(GRID_AUX, 0, -1, 1);                // D0: fps c0 + aux
  LAUNCH(GRID_MAIN, 1, 0, 0);                // D1: fps c1 + fuse c0
  LAUNCH(GRID_MAIN, 2, 1, 0);                // D2
  LAUNCH(GRID_MAIN, 3, 2, 0);                // D3
  LAUNCH(GRID_MAIN, 4, 3, 0);                // D4
  LAUNCH(GRID_MAIN, 5, 4, 0);                // D5
  LAUNCH(GRID_MAIN, 6, 5, 0);                // D6
  LAUNCH(GRID_MAIN, 7, 6, 0);                // D7
  LAUNCH(GRID_MAIN, -1, 7, 0);               // D8: fuse c7 (tail)
#undef LAUNCH
}

// Round 9
// 900.212 us; speedup vs baseline: 1.1241x; 1.1241x over previous
//
#include <hip/hip_runtime.h>
#include <math.h>

#define BB 8
#define NN 4096
#define CC 256
#define DD 64
#define MM 1024
#define KNB 16
#define OC 259
#define CHUNK 128
#define NCHUNK 8

typedef unsigned long long ull;

// Dispatch roles (main grid 1032, aux dispatch 2585):
//   blk [0,8)       : FPS chunk c_fps (8 blocks, 1 batch each)
//   aux dispatch    : blk [8,2585) -> 2577 aux units
//   main dispatches : blk [8,1032) -> merged KNN+fuse chunk c_fuse
//                     (1024 blocks; 4-wave cooperative KNN ~6us, then fuse)
// Pipeline lag 1: D_c = FPS c || mfuse c-1. Tail = ONE mfuse dispatch.
// Static LDS = 49,728 B (FPS role; mfuse = 35,664 with KNN dbuf aliased
// over W12_l) -> 3 blocks/CU with __launch_bounds__(256,3).
#define GRID_MAIN 1032
#define GRID_AUX 2585
#define AUX_G2 512

// ---------------------------------------------------------------------------
// aux units (verbatim from verified round-0 phase1 roles) ----------------
__device__ __forceinline__ void g2_unit(
    int u, int tid, char* smem, const float* fm, const float* aw1,
    const float* g2v, const float* v2, float* G2) {
  float (*a_l)[68] = (float(*)[68])smem;
  float (*b_l)[68] = (float(*)[68])(smem + 64 * 68 * 4);
  int b = u >> 6;
  int n0 = (u & 63) * 64;
  int rr = tid >> 4, q4 = tid & 15;
  float s2v[4];
#pragma unroll
  for (int j = 0; j < 4; ++j)
    s2v[j] = g2v[q4 * 4 + j] * rsqrtf(v2[q4 * 4 + j] + 1e-5f);
  float acc[4][4];
#pragma unroll
  for (int q = 0; q < 4; ++q)
#pragma unroll
    for (int x = 0; x < 4; ++x) acc[q][x] = 0.f;
  for (int c0 = 0; c0 < 256; c0 += 64) {
    __syncthreads();
#pragma unroll
    for (int rep = 0; rep < 4; ++rep) {
      int cc = rr + rep * 16;
      *(float4*)&a_l[cc][q4 * 4] =
          *(const float4*)&fm[((size_t)b * CC + c0 + cc) * NN + n0 + q4 * 4];
      float bv[4];
#pragma unroll
      for (int j = 0; j < 4; ++j)
        bv[j] = aw1[(q4 * 4 + j) * 256 + c0 + cc] * s2v[j];
      *(float4*)&b_l[cc][q4 * 4] = make_float4(bv[0], bv[1], bv[2], bv[3]);
    }
    __syncthreads();
#pragma unroll 8
    for (int kk = 0; kk < 64; ++kk) {
      float4 a4 = *(const float4*)&a_l[kk][rr * 4];
      float4 b4 = *(const float4*)&b_l[kk][q4 * 4];
      float av[4] = {a4.x, a4.y, a4.z, a4.w};
#pragma unroll
      for (int q = 0; q < 4; ++q) {
        acc[q][0] += av[q] * b4.x;
        acc[q][1] += av[q] * b4.y;
        acc[q][2] += av[q] * b4.z;
        acc[q][3] += av[q] * b4.w;
      }
    }
  }
#pragma unroll
  for (int q = 0; q < 4; ++q)
    *(float4*)&G2[((size_t)b * NN + n0 + rr * 4 + q) * 64 + q4 * 4] =
        make_float4(acc[q][0], acc[q][1], acc[q][2], acc[q][3]);
}

__device__ __forceinline__ void prep_unit(
    int tid, const float* pw1, const float* pb1, const float* g1,
    const float* bb1, const float* m1, const float* v1, const float* pw2,
    const float* aw1, const float* g2v, const float* bb2, const float* m2,
    const float* v2, const float* aw2, const float* ab1, float* w1f,
    float* b1f, float* ab1f, float* pw2t, float* aw1t, float* aw2t) {
  if (tid < 64) {
    float s = g1[tid] * rsqrtf(v1[tid] + 1e-5f);
    w1f[tid * 4 + 0] = pw1[tid * 3 + 0] * s;
    w1f[tid * 4 + 1] = pw1[tid * 3 + 1] * s;
    w1f[tid * 4 + 2] = pw1[tid * 3 + 2] * s;
    w1f[tid * 4 + 3] = 0.f;
    b1f[tid] = (pb1[tid] - m1[tid]) * s + bb1[tid];
    float s2 = g2v[tid] * rsqrtf(v2[tid] + 1e-5f);
    ab1f[tid] = (ab1[tid] - m2[tid]) * s2 + bb2[tid];
  }
  for (int x = tid; x < 64 * 256; x += 256) {
    int i = x >> 8, c = x & 255;
    pw2t[x] = pw2[c * 64 + i];
  }
  for (int x = tid; x < 256 * 64; x += 256) {
    int c = x >> 6, d = x & 63;
    float s2 = g2v[d] * rsqrtf(v2[d] + 1e-5f);
    aw1t[x] = aw1[d * 256 + c] * s2;
  }
  for (int x = tid; x < 64 * OC; x += 256) {
    int i = x / OC, o = x % OC;
    aw2t[i * 260 + o] = aw2[o * 64 + i];
  }
}

__device__ __forceinline__ void w12_unit(
    int w, int tid, const float* pw2, const float* aw1, const float* g2v,
    const float* v2, float* W12t) {
  int i = tid & 63;
  int d = w * 4 + (tid >> 6);
  float s2 = g2v[d] * rsqrtf(v2[d] + 1e-5f);
  const float* arow = aw1 + d * 256;
  float s = 0.f;
#pragma unroll 4
  for (int c = 0; c < 256; ++c) s += pw2[c * 64 + i] * arow[c];
  W12t[i * 64 + d] = s * s2;
}

__device__ __forceinline__ void transpose_unit(
    int rb, int tid, char* smem, const float* fm, float* fm_t) {
  float (*tile)[65] = (float(*)[65])smem;
  int b = rb >> 8;
  int rem = rb & 255;
  int c0 = (rem >> 6) * 64;
  int n0 = (rem & 63) * 64;
  const float* src = fm + (size_t)b * CC * NN;
  float* dst = fm_t + (size_t)b * NN * CC;
  int tx = tid & 63, ty = tid >> 6;
  for (int r = ty; r < 64; r += 4)
    tile[r][tx] = src[(size_t)(c0 + r) * NN + n0 + tx];
  __syncthreads();
  for (int r = ty; r < 64; r += 4)
    dst[(size_t)(n0 + r) * CC + c0 + tx] = tile[tx][r];
}

// 4-wave cooperative KNN: identical candidate coverage, two-best tracking,
// (dist,idx) lexicographic selection and pop/refill semantics as the
// verified 1-wave version; candidates split 16/lane across 4 waves with a
// 4-entry LDS exchange for the global winner.
__device__ __forceinline__ void knn4(
    int b, int m, int tid, float* dbuf, float* candv, int* candi,
    int* kidx, const float* verts, const int* fpsi) {
  int wave = tid >> 6, lane = tid & 63;
  const float* vb = verts + (size_t)b * 3 * NN;
  int jm = fpsi[b * MM + m];
  float kx = vb[jm], ky = vb[NN + jm], kz = vb[2 * NN + jm];
  float kn = kx * kx + ky * ky + kz * kz;
  float* mybuf = dbuf + (wave * 64 + lane) * 17;
  float v1 = INFINITY, v2 = INFINITY;
  int i1 = -1, i2 = -1;
#pragma unroll 4
  for (int t = 0; t < 16; ++t) {
    int j = (wave * 16 + t) * 64 + lane;
    float x = vb[j], y = vb[NN + j], z = vb[2 * NN + j];
    float xn = x * x + y * y + z * z;
    float d = kn + xn - 2.0f * (kx * x + ky * y + kz * z);
    mybuf[t] = d;
    if (d < v1) { v2 = v1; i2 = i1; v1 = d; i1 = j; }
    else if (d < v2) { v2 = d; i2 = j; }
  }
  for (int it = 0; it < KNB; ++it) {
    float rv = v1;
    int ri = i1;
#pragma unroll
    for (int off = 32; off >= 1; off >>= 1) {
      float ov = __shfl_down(rv, off, 64);
      int oi = __shfl_down(ri, off, 64);
      if (ov < rv || (ov == rv && oi < ri)) { rv = ov; ri = oi; }
    }
    if (lane == 0) { candv[wave] = rv; candi[wave] = ri; }
    __syncthreads();
    float bv = candv[0];
    int bi = candi[0];
#pragma unroll
    for (int w = 1; w < 4; ++w) {
      float wv = candv[w];
      int wi = candi[w];
      if (wv < bv || (wv == bv && wi < bi)) { bv = wv; bi = wi; }
    }
    if (tid == 0) kidx[it] = bi;
    __syncthreads();  // cand slots consumed; safe to rewrite next iteration
    if (i1 == bi) {   // unique owning lane (j determines wave+lane)
      mybuf[(bi >> 6) & 15] = INFINITY;
      v1 = v2; i1 = i2;
      v2 = INFINITY; i2 = -1;
      if (i1 < 0) {
#pragma unroll 4
        for (int t = 0; t < 16; ++t) {
          float d = mybuf[t];
          int j = (wave * 16 + t) * 64 + lane;
          if (d < v1) { v2 = v1; i2 = i1; v1 = d; i1 = j; }
          else if (d < v2) { v2 = d; i2 = j; }
        }
      }
    }
  }
}

// fuse item (phase B verbatim from round-7 PASSED kernel; phase A = knn4,
// dbuf aliased over W12_l which is only written after a later barrier)
struct FuseS {                 // 35,664 B
  float W12_l[64][68];         // phase A: aliased as KNN dbuf (17,408 B)
  float h_l[16][68];
  float hT_l[64][20];
  float h2T_l[64][20];
  float vmp[4][64];
  float vm_l[64];
  float kfpb[256];
  float pb2_l[256];
  float gp[3][16];
  float kp[4];
  int kidx[16];
  float candv[4];
  int candi[4];
};

__device__ __forceinline__ void fuse_item(
    int b, int m, int tid, char* smem, const float* verts,
    const float* fm_t, const float* G2, const int* fpsi,
    const float* w1f, const float* b1f, const float* ab1f,
    const float* aw1t, const float* W12t, const float* pw2t,
    const float* pb2, const float* aw2t, const float* ab2, float* out) {
  FuseS* S = (FuseS*)smem;
  const float* vb = verts + (size_t)b * 3 * NN;
  const float* fb = fm_t + (size_t)b * NN * CC;

  // ---- phase A: all 4 waves cooperatively compute 16-NN into S->kidx.
  knn4(b, m, tid, (float*)S->W12_l, S->candv, S->candi, S->kidx,
       verts, fpsi);
  __syncthreads();

  // ---- phase B: verbatim fuse body (kidx already in LDS).
  int jm = fpsi[b * MM + m];
  S->kfpb[tid] = fb[(size_t)jm * CC + tid] + pb2[tid];
  S->pb2_l[tid] = pb2[tid];
  if (tid < 3) S->kp[tid] = vb[tid * NN + jm];
  __syncthreads();

  if (tid < 48) {
    int c = tid >> 4, k = tid & 15;
    S->gp[c][k] = vb[c * NN + S->kidx[k]];
  }
  {
    int i = tid >> 4, d4 = tid & 15;
#pragma unroll
    for (int rep = 0; rep < 4; ++rep)
      *(float4*)&S->W12_l[i + rep * 16][d4 * 4] =
          *(const float4*)&W12t[(i + rep * 16) * 64 + d4 * 4];
  }
  {
    int d = tid & 63, part = tid >> 6;
    float acc = 0.f;
#pragma unroll 4
    for (int cc = 0; cc < 64; ++cc) {
      int c = part * 64 + cc;
      acc += aw1t[c * 64 + d] * S->kfpb[c];
    }
    S->vmp[part][d] = acc;
  }
  __syncthreads();
  if (tid < 64)
    S->vm_l[tid] = S->vmp[0][tid] + S->vmp[1][tid] + S->vmp[2][tid] +
                   S->vmp[3][tid] + ab1f[tid];

  {
    int d = tid & 63, part = tid >> 6;
    float wd0 = w1f[d * 4 + 0], wd1 = w1f[d * 4 + 1], wd2 = w1f[d * 4 + 2];
    float bd = b1f[d];
#pragma unroll
    for (int j = 0; j < 4; ++j) {
      int k = part * 4 + j;
      float hv = wd0 * (S->kp[0] - S->gp[0][k]) +
                 wd1 * (S->kp[1] - S->gp[1][k]) +
                 wd2 * (S->kp[2] - S->gp[2][k]) + bd;
      hv = (hv > 0.f) ? hv : 0.2f * hv;
      S->h_l[k][d] = hv;
      S->hT_l[d][k] = hv;
    }
  }
  __syncthreads();

  {
    int k = tid & 15, d2 = tid >> 4;
    float4 g4 =
        *(const float4*)&G2[((size_t)b * NN + S->kidx[k]) * 64 + d2 * 4];
    float a0 = 0.f, a1 = 0.f, a2 = 0.f, a3 = 0.f;
#pragma unroll 4
    for (int i = 0; i < 64; ++i) {
      float hv = S->h_l[k][i];
      float4 w4 = *(const float4*)&S->W12_l[i][d2 * 4];
      a0 += hv * w4.x; a1 += hv * w4.y; a2 += hv * w4.z; a3 += hv * w4.w;
    }
    float4 v4 = *(const float4*)&S->vm_l[d2 * 4];
    float r0 = v4.x - g4.x + a0;
    float r1 = v4.y - g4.y + a1;
    float r2 = v4.z - g4.z + a2;
    float r3 = v4.w - g4.w + a3;
    S->h2T_l[d2 * 4 + 0][k] = (r0 > 0.f) ? r0 : 0.2f * r0;
    S->h2T_l[d2 * 4 + 1][k] = (r1 > 0.f) ? r1 : 0.2f * r1;
    S->h2T_l[d2 * 4 + 2][k] = (r2 > 0.f) ? r2 : 0.2f * r2;
    S->h2T_l[d2 * 4 + 3][k] = (r3 > 0.f) ? r3 : 0.2f * r3;
  }
  __syncthreads();

  if (tid < 3) {
    float lg[16];
    float bias = ab2[tid];
#pragma unroll
    for (int k = 0; k < 16; ++k) lg[k] = bias;
    const float* wp = aw2t + tid;
    for (int i = 0; i < 64; ++i) {
      float wv = wp[i * 260];
      float4 ha = *(const float4*)&S->h2T_l[i][0];
      float4 hb = *(const float4*)&S->h2T_l[i][4];
      float4 hc = *(const float4*)&S->h2T_l[i][8];
      float4 hd = *(const float4*)&S->h2T_l[i][12];
      lg[0] += wv * ha.x;  lg[1] += wv * ha.y;  lg[2] += wv * ha.z;  lg[3] += wv * ha.w;
      lg[4] += wv * hb.x;  lg[5] += wv * hb.y;  lg[6] += wv * hb.z;  lg[7] += wv * hb.w;
      lg[8] += wv * hc.x;  lg[9] += wv * hc.y;  lg[10] += wv * hc.z; lg[11] += wv * hc.w;
      lg[12] += wv * hd.x; lg[13] += wv * hd.y; lg[14] += wv * hd.z; lg[15] += wv * hd.w;
    }
    float mx = lg[0];
#pragma unroll
    for (int k = 1; k < 16; ++k) mx = fmaxf(mx, lg[k]);
    float sum = 0.f;
#pragma unroll
    for (int k = 0; k < 16; ++k) { lg[k] = __expf(lg[k] - mx); sum += lg[k]; }
    float inv = 1.f / sum;
    float a2 = 0.f;
#pragma unroll
    for (int k = 0; k < 16; ++k) a2 += lg[k] * S->gp[tid][k];
    out[((size_t)b * OC + tid) * MM + m] = a2 * inv;
  }

  {
    int o = tid + 3;
    float gfv[16];
#pragma unroll
    for (int k = 0; k < 16; ++k)
      gfv[k] = fb[(size_t)S->kidx[k] * CC + tid];
    float lg[16];
    float bias = ab2[o];
#pragma unroll
    for (int k = 0; k < 16; ++k) lg[k] = bias;
    const float* wp = aw2t + o;
#pragma unroll 4
    for (int i = 0; i < 64; ++i) {
      float wv = wp[i * 260];
      float4 ha = *(const float4*)&S->h2T_l[i][0];
      float4 hb = *(const float4*)&S->h2T_l[i][4];
      float4 hc = *(const float4*)&S->h2T_l[i][8];
      float4 hd = *(const float4*)&S->h2T_l[i][12];
      lg[0] += wv * ha.x;  lg[1] += wv * ha.y;  lg[2] += wv * ha.z;  lg[3] += wv * ha.w;
      lg[4] += wv * hb.x;  lg[5] += wv * hb.y;  lg[6] += wv * hb.z;  lg[7] += wv * hb.w;
      lg[8] += wv * hc.x;  lg[9] += wv * hc.y;  lg[10] += wv * hc.z; lg[11] += wv * hc.w;
      lg[12] += wv * hd.x; lg[13] += wv * hd.y; lg[14] += wv * hd.z; lg[15] += wv * hd.w;
    }
    float mx = lg[0];
#pragma unroll
    for (int k = 1; k < 16; ++k) mx = fmaxf(mx, lg[k]);
    float sum = 0.f;
#pragma unroll
    for (int k = 0; k < 16; ++k) { lg[k] = __expf(lg[k] - mx); sum += lg[k]; }
    float inv = 1.f / sum;
#pragma unroll
    for (int k = 0; k < 16; ++k) lg[k] *= inv;
    float acc = 0.f;
#pragma unroll
    for (int k = 0; k < 16; ++k) acc += lg[k] * gfv[k];
    const float* pcol = pw2t + tid;
#pragma unroll 4
    for (int i = 0; i < 64; ++i) {
      float p = pcol[i * 256];
      float4 ha = *(const float4*)&S->hT_l[i][0];
      float4 hb = *(const float4*)&S->hT_l[i][4];
      float4 hc = *(const float4*)&S->hT_l[i][8];
      float4 hd = *(const float4*)&S->hT_l[i][12];
      float hw = lg[0] * ha.x + lg[1] * ha.y + lg[2] * ha.z + lg[3] * ha.w +
                 lg[4] * hb.x + lg[5] * hb.y + lg[6] * hb.z + lg[7] * hb.w +
                 lg[8] * hc.x + lg[9] * hc.y + lg[10] * hc.z + lg[11] * hc.w +
                 lg[12] * hd.x + lg[13] * hd.y + lg[14] * hd.z + lg[15] * hd.w;
      acc += p * hw;
    }
    out[((size_t)b * OC + o) * MM + m] = S->pb2_l[tid] + acc;
  }
}

// ---------------------------------------------------------------------------
// Pipelined dispatch kernel, lag-1: dispatch boundaries order
// FPS chunk c -> mfuse chunk c (next dispatch; KNN by all 4 waves in-block).
__global__ __launch_bounds__(256, 3) void pipe(
    const float* __restrict__ verts, const float* __restrict__ fm,
    const float* __restrict__ pw1, const float* __restrict__ pb1,
    const float* __restrict__ g1, const float* __restrict__ bb1,
    const float* __restrict__ m1, const float* __restrict__ v1,
    const float* __restrict__ pw2, const float* __restrict__ pb2,
    const float* __restrict__ aw1, const float* __restrict__ ab1,
    const float* __restrict__ g2v, const float* __restrict__ bb2,
    const float* __restrict__ m2, const float* __restrict__ v2,
    const float* __restrict__ aw2, const float* __restrict__ ab2,
    float* __restrict__ fm_t, float* __restrict__ G2,
    int* __restrict__ fpsi,
    float* __restrict__ w1f, float* __restrict__ b1f,
    float* __restrict__ ab1f, float* __restrict__ pw2t,
    float* __restrict__ aw1t, float* __restrict__ aw2t,
    float* __restrict__ W12t, float* __restrict__ dstate,
    int* __restrict__ fstate, float* __restrict__ out,
    int c_fps, int c_fuse, int aux_flag) {
  __shared__ __align__(16) char smem[49728];
  int blk = blockIdx.x;
  int tid = threadIdx.x;

  if (blk < 8) {
    // ---- FPS chunk (v5 loop body; indices buffered in LDS, bulk-stored)
    if (c_fps < 0) return;
    float* lx = (float*)smem;
    float* ly = lx + NN;
    float* lz = ly + NN;
    ull* wres = (ull*)(lz + NN);        // [2][4] = 64 B
    int* fps_l = (int*)(wres + 8);      // [CHUNK] = 512 B
    int b = blk;
    const float* vb = verts + (size_t)b * 3 * NN;
    float px[16], py[16], pz[16], dist[16];
#pragma unroll
    for (int r = 0; r < 16; ++r) {
      int j = tid + r * 256;
      px[r] = vb[j]; py[r] = vb[NN + j]; pz[r] = vb[2 * NN + j];
      lx[j] = px[r]; ly[j] = py[r]; lz[j] = pz[r];
    }
    int far;
    if (c_fps == 0) {
#pragma unroll
      for (int r = 0; r < 16; ++r) dist[r] = 1e10f;
      far = 0;
    } else {
#pragma unroll
      for (int r = 0; r < 16; ++r)
        dist[r] = dstate[(size_t)b * NN + tid + r * 256];
      far = fstate[b];
    }
    __syncthreads();
    int s0 = c_fps * CHUNK, s1 = s0 + CHUNK;
    for (int s = s0; s < s1; ++s) {
      if (tid == 0) fps_l[s - s0] = far;
      if (s == MM - 1) break;
      float cx = lx[far], cy = ly[far], cz = lz[far];
      float vmax = -1.0f;
#pragma unroll
      for (int r = 0; r < 16; ++r) {
        float dx = px[r] - cx, dy = py[r] - cy, dz = pz[r] - cz;
        float d = dx * dx + dy * dy + dz * dz;
        dist[r] = fminf(dist[r], d);
        vmax = fmaxf(vmax, dist[r]);
      }
#define VRED(CTRL)                                                            \
      {                                                                       \
        int o = __builtin_amdgcn_update_dpp(__float_as_int(vmax),             \
                                            __float_as_int(vmax), CTRL, 0xF,  \
                                            0xF, false);                      \
        vmax = fmaxf(vmax, __int_as_float(o));                                \
      }
      VRED(0x111) VRED(0x112) VRED(0x114) VRED(0x118) VRED(0x142) VRED(0x143)
#undef VRED
      float svmax =
          __int_as_float(__builtin_amdgcn_readlane(__float_as_int(vmax), 63));
      int minj = 0x7FFFFFFF;
#pragma unroll
      for (int r = 0; r < 16; ++r) {
        int cand = (dist[r] == svmax) ? (tid + r * 256) : 0x7FFFFFFF;
        minj = (cand < minj) ? cand : minj;
      }
#define IRED(CTRL)                                                            \
      {                                                                       \
        int o = __builtin_amdgcn_update_dpp(minj, minj, CTRL, 0xF, 0xF,       \
                                            false);                          \
        minj = (o < minj) ? o : minj;                                         \
      }
      IRED(0x111) IRED(0x112) IRED(0x114) IRED(0x118) IRED(0x142) IRED(0x143)
#undef IRED
      if ((tid & 63) == 63)
        wres[(s & 1) * 4 + (tid >> 6)] =
            ((ull)(unsigned)__float_as_int(svmax) << 12) |
            (ull)(4095 - minj);
      __syncthreads();
      int p = s & 1;
      ull k0 = wres[p * 4 + 0], k1 = wres[p * 4 + 1];
      ull k2 = wres[p * 4 + 2], k3 = wres[p * 4 + 3];
      ull a = (k0 > k1) ? k0 : k1;
      ull c = (k2 > k3) ? k2 : k3;
      a = (c > a) ? c : a;
      far = 4095 - (int)(a & 0xFFFull);
    }
    __syncthreads();
    for (int x = tid; x < CHUNK; x += 256) fpsi[b * MM + s0 + x] = fps_l[x];
    if (s1 < MM) {
#pragma unroll
      for (int r = 0; r < 16; ++r)
        dstate[(size_t)b * NN + tid + r * 256] = dist[r];
      if (tid == 0) fstate[b] = far;
    }
    return;
  }

  if (aux_flag) {
    // ---- D0 aux: u in [0,2577)
    int u = blk - 8;
    if (u < AUX_G2) {
      g2_unit(u, tid, smem, fm, aw1, g2v, v2, G2);
    } else if (u == AUX_G2) {
      prep_unit(tid, pw1, pb1, g1, bb1, m1, v1, pw2, aw1, g2v, bb2, m2, v2,
                aw2, ab1, w1f, b1f, ab1f, pw2t, aw1t, aw2t);
    } else if (u < AUX_G2 + 17) {
      w12_unit(u - (AUX_G2 + 1), tid, pw2, aw1, g2v, v2, W12t);
    } else {
      transpose_unit(u - (AUX_G2 + 17), tid, smem, fm, fm_t);
    }
    return;
  }

  {
    // ---- merged KNN+fuse chunk: 1024 blocks = 8 b x 128 m
    if (c_fuse < 0) return;
    int e = blk - 8;
    int b = e & 7;
    int m = c_fuse * CHUNK + (e >> 3);
    fuse_item(b, m, tid, smem, verts, fm_t, G2, fpsi, w1f, b1f, ab1f,
              aw1t, W12t, pw2t, pb2, aw2t, ab2, out);
  }
}

// ---------------------------------------------------------------------------
extern "C" void kernel_launch(void* const* d_in, const int* in_sizes, int n_in,
                              void* d_out, int out_size, void* d_ws,
                              size_t ws_size, hipStream_t stream) {
  (void)in_sizes; (void)n_in; (void)out_size; (void)ws_size;
  const float* verts = (const float*)d_in[0];
  const float* fm = (const float*)d_in[1];
  const float* pw1 = (const float*)d_in[2];
  const float* pb1 = (const float*)d_in[3];
  const float* g1 = (const float*)d_in[4];
  const float* bb1 = (const float*)d_in[5];
  const float* m1 = (const float*)d_in[6];
  const float* v1 = (const float*)d_in[7];
  const float* pw2 = (const float*)d_in[8];
  const float* pb2 = (const float*)d_in[9];
  const float* aw1 = (const float*)d_in[10];
  const float* ab1 = (const float*)d_in[11];
  const float* g2 = (const float*)d_in[12];
  const float* bb2 = (const float*)d_in[13];
  const float* m2 = (const float*)d_in[14];
  const float* v2 = (const float*)d_in[15];
  const float* aw2 = (const float*)d_in[16];
  const float* ab2 = (const float*)d_in[17];
  float* out = (float*)d_out;

  char* ws = (char*)d_ws;
  float* fm_t = (float*)ws;                               // 33,554,432 B
  float* G2 = (float*)(ws + 33554432);                    //  8,388,608 B
  int* fpsi = (int*)(ws + 41943040);                      //     32,768 B
  float* w1f = (float*)(ws + 42500096);
  float* b1f = w1f + 256;
  float* ab1f = b1f + 64;
  float* pw2t = ab1f + 64;
  float* aw1t = pw2t + 64 * 256;
  float* aw2t = aw1t + 256 * 64;
  float* W12t = aw2t + 64 * 260;
  float* dstate = (float*)(ws + 42715648);                //    131,072 B
  int* fstate = (int*)(ws + 42846720);                    //         32 B

#define LAUNCH(grid, cf, cz, ax)                                              \
  hipLaunchKernelGGL(pipe, dim3(grid), dim3(256), 0, stream, verts, fm, pw1,  \
                     pb1, g1, bb1, m1, v1, pw2, pb2, aw1, ab1, g2, bb2, m2,   \
                     v2, aw2, ab2, fm_t, G2, fpsi, w1f, b1f, ab1f,            \
                     pw2t, aw1t, aw2t, W12t, dstate, fstate, out, cf, cz, ax)

  LAUNCH(GRID_AUX, 0, -1, 1);                // D0: fps c0 + aux
  LAUNCH(GRID_MAIN, 1, 0, 0);                // D1: fps c1 + mfuse c0
  LAUNCH(GRID_MAIN, 2, 1, 0);                // D2
  LAUNCH(GRID_MAIN, 3, 2, 0);                // D3
  LAUNCH(GRID_MAIN, 4, 3, 0);                // D4
  LAUNCH(GRID_MAIN, 5, 4, 0);                // D5
  LAUNCH(GRID_MAIN, 6, 5, 0);                // D6
  LAUNCH(GRID_MAIN, 7, 6, 0);                // D7
  LAUNCH(GRID_MAIN, -1, 7, 0);               // D8: mfuse c7 (tail)
#undef LAUNCH
}